// Round 6
// baseline (77.296 us; speedup 1.0000x reference)
//
#include <hip/hip_runtime.h>

#define ALPHA 0.2f
#define BATCH 16
#define WIN 100
#define KN 128          // nodes
#define DE 200          // embed dim
#define IT 8            // i-tile per block
#define NBLK 256

typedef float v2f __attribute__((ext_vector_type(2)));

// One fused kernel. 256 blocks x 512 thr, all co-resident (81.8KB LDS -> <=2/CU,
// capacity 512 >= 256). Phase 1 writes Rt grid-wide; software grid barrier
// (device-scope atomics, counter zeroed by a memset node); phase 2 = e/softmax/PV.
__global__ __launch_bounds__(512) void k_fused(
    const float* __restrict__ in, const float* __restrict__ lw,
    const float* __restrict__ lb, const float* __restrict__ aw,
    float* Rt, float* __restrict__ out, unsigned int* ctr) {
  int blk = blockIdx.x;
  int t = threadIdx.x;
  int b = blk >> 4, it = blk & 15, i0 = it * IT;

  __shared__ float xs[WIN * 132];      // [w][j] stride 132
  __shared__ float Lis[DE][IT];        // [d][ii], 32B rows (broadcast reads)
  __shared__ float part[4][IT][KN];
  __shared__ float part_r[4][KN];
  __shared__ float ats[IT][132];

  // --- stage xs (independent of barrier) ---
  const float* inb = in + (size_t)b * WIN * KN;
#pragma unroll
  for (int k = 0; k < 7; ++k) {
    int i4 = t + k * 512;
    if (i4 < WIN * KN / 4) {
      int w = i4 >> 5, jq = (i4 & 31) << 2;
      *reinterpret_cast<float4*>(&xs[w * 132 + jq]) =
          reinterpret_cast<const float4*>(inb)[i4];
    }
  }

  // --- phase 1: Rt[bb][d][j] slice; note bb == b for every thread of this block ---
  {
    int g = blk * 512 + t;
    int j = g & 127;
    int q = g >> 7;              // wave-uniform
    int bb = q >> 6;             // == b
    int r = q & 63;              // d = r + 64k
    const float* xcol = in + (size_t)bb * WIN * KN + j;
    const float* lwr = lw + WIN * DE + r;
    float* rp = Rt + ((size_t)bb * DE + r) * KN + j;
    if (r < 8) {
      float a0 = 0, a1 = 0, a2 = 0, a3 = 0;
#pragma unroll 2
      for (int w = 0; w < WIN; ++w) {
        float x = xcol[w * KN];
        const float* row = lwr + w * DE;
        a0 = fmaf(x, row[0], a0);   a1 = fmaf(x, row[64], a1);
        a2 = fmaf(x, row[128], a2); a3 = fmaf(x, row[192], a3);
      }
      rp[0] = a0 + lb[r];
      rp[(size_t)64 * KN] = a1 + lb[r + 64];
      rp[(size_t)128 * KN] = a2 + lb[r + 128];
      rp[(size_t)192 * KN] = a3 + lb[r + 192];
    } else {
      float a0 = 0, a1 = 0, a2 = 0;
#pragma unroll 2
      for (int w = 0; w < WIN; ++w) {
        float x = xcol[w * KN];
        const float* row = lwr + w * DE;
        a0 = fmaf(x, row[0], a0);   a1 = fmaf(x, row[64], a1);
        a2 = fmaf(x, row[128], a2);
      }
      rp[0] = a0 + lb[r];
      rp[(size_t)64 * KN] = a1 + lb[r + 64];
      rp[(size_t)128 * KN] = a2 + lb[r + 128];
    }
  }

  // --- phase 1b: local Li for this block's 8 i's (overlaps barrier wait) ---
  for (int idx = t; idx < IT * DE; idx += 512) {
    int ii = idx / DE;           // consecutive idx -> consecutive d (coalesced lw)
    int d = idx - ii * DE;
    const float* xc = in + (size_t)b * WIN * KN + i0 + ii;
    const float* lc = lw + d;
    float a = 0.f;
#pragma unroll 4
    for (int w = 0; w < WIN; ++w)
      a = fmaf(xc[w * KN], lc[w * DE], a);
    Lis[d][ii] = a;
  }

  // --- grid barrier: release Rt, arrive, spin, acquire ---
  __syncthreads();                       // drains each wave's stores (vmcnt 0)
  if (t == 0) {
    __threadfence();                     // L2 writeback (agent scope)
    __hip_atomic_fetch_add(ctr, 1u, __ATOMIC_ACQ_REL, __HIP_MEMORY_SCOPE_AGENT);
    while (__hip_atomic_load(ctr, __ATOMIC_ACQUIRE, __HIP_MEMORY_SCOPE_AGENT) < NBLK)
      __builtin_amdgcn_s_sleep(8);
    __threadfence();                     // invalidate vector caches
  }
  __syncthreads();

  // --- e-phase: thread (j, dh) covers 50 d's for 8 i's ---
  {
    int j = t & (KN - 1);
    int dh = t >> 7;                     // wave-uniform
    int db = dh * 50;
    const float* rtb = Rt + (size_t)b * DE * KN + j;
    v2f acc0 = 0.f, acc1 = 0.f, acc2 = 0.f, acc3 = 0.f;
    float racc = 0.f;
#pragma unroll 2
    for (int dd = 0; dd < 50; ++dd) {
      int d = db + dd;
      float r = rtb[(size_t)d * KN];
      float a = aw[d];
      float4 L0 = *reinterpret_cast<const float4*>(&Lis[d][0]);
      float4 L1 = *reinterpret_cast<const float4*>(&Lis[d][4]);
      racc = fmaf(r, a, racc);
      v2f rv = {r, r}, av = {a, a}, z = 0.f;
      v2f p0 = (v2f){L0.x, L0.y} + rv;
      v2f p1 = (v2f){L0.z, L0.w} + rv;
      v2f p2 = (v2f){L1.x, L1.y} + rv;
      v2f p3 = (v2f){L1.z, L1.w} + rv;
      p0 = __builtin_elementwise_min(p0, z);
      p1 = __builtin_elementwise_min(p1, z);
      p2 = __builtin_elementwise_min(p2, z);
      p3 = __builtin_elementwise_min(p3, z);
      acc0 += p0 * av; acc1 += p1 * av; acc2 += p2 * av; acc3 += p3 * av;
    }
    part[dh][0][j] = acc0.x; part[dh][1][j] = acc0.y;
    part[dh][2][j] = acc1.x; part[dh][3][j] = acc1.y;
    part[dh][4][j] = acc2.x; part[dh][5][j] = acc2.y;
    part[dh][6][j] = acc3.x; part[dh][7][j] = acc3.y;
    part_r[dh][j] = racc;
  }
  __syncthreads();

  // --- softmax: wave r owns row r (e differs from ref by a per-i constant:
  //     the sum_d Li*aw term is j-invariant -> softmax unchanged) ---
  {
    int r = t >> 6, l = t & 63;
    float ra0 = part_r[0][l] + part_r[1][l] + part_r[2][l] + part_r[3][l];
    float ra1 = part_r[0][l + 64] + part_r[1][l + 64] + part_r[2][l + 64] + part_r[3][l + 64];
    float m0 = part[0][r][l] + part[1][r][l] + part[2][r][l] + part[3][r][l];
    float m1 = part[0][r][l + 64] + part[1][r][l + 64] + part[2][r][l + 64] + part[3][r][l + 64];
    float e0 = fmaf(m0, -(1.f - ALPHA), ra0);
    float e1 = fmaf(m1, -(1.f - ALPHA), ra1);
    float m = fmaxf(e0, e1);
    for (int off = 32; off; off >>= 1) m = fmaxf(m, __shfl_xor(m, off));
    float p0 = __expf(e0 - m), p1 = __expf(e1 - m);
    float s = p0 + p1;
    for (int off = 32; off; off >>= 1) s += __shfl_xor(s, off);
    float inv = 1.f / s;
    ats[r][l] = p0 * inv;
    ats[r][l + 64] = p1 * inv;
  }
  __syncthreads();

  // --- PV + sigmoid + store ---
  if (t < 4 * WIN) {
    int w = t >> 2, q = t & 3;
    const float* xw = &xs[w * 132];
    const float* a0p = &ats[q * 2][0];
    const float* a1p = &ats[q * 2 + 1][0];
    float s0 = 0.f, s1 = 0.f;
#pragma unroll 8
    for (int j = 0; j < KN; j += 4) {
      float4 x4 = *reinterpret_cast<const float4*>(xw + j);
      float4 aa = *reinterpret_cast<const float4*>(a0p + j);
      float4 ab = *reinterpret_cast<const float4*>(a1p + j);
      s0 = fmaf(aa.x, x4.x, s0); s0 = fmaf(aa.y, x4.y, s0);
      s0 = fmaf(aa.z, x4.z, s0); s0 = fmaf(aa.w, x4.w, s0);
      s1 = fmaf(ab.x, x4.x, s1); s1 = fmaf(ab.y, x4.y, s1);
      s1 = fmaf(ab.z, x4.z, s1); s1 = fmaf(ab.w, x4.w, s1);
    }
    float o0 = 1.f / (1.f + __expf(-s0));
    float o1 = 1.f / (1.f + __expf(-s1));
    *reinterpret_cast<float2*>(&out[((size_t)b * WIN + w) * KN + i0 + q * 2]) =
        make_float2(o0, o1);
  }
}

extern "C" void kernel_launch(void* const* d_in, const int* in_sizes, int n_in,
                              void* d_out, int out_size, void* d_ws, size_t ws_size,
                              hipStream_t stream) {
  const float* in = (const float*)d_in[0];   // (16,100,128)
  const float* lw = (const float*)d_in[1];   // (200,200)
  const float* lb = (const float*)d_in[2];   // (200,)
  const float* aw = (const float*)d_in[3];   // (200,)
  float* out = (float*)d_out;                // (16,100,128)

  float* Rt = (float*)d_ws;                                   // 16*200*128 floats
  unsigned int* ctr =
      (unsigned int*)((char*)d_ws + (size_t)BATCH * DE * KN * sizeof(float));

  hipMemsetAsync(ctr, 0, sizeof(unsigned int), stream);       // graph-safe reset
  k_fused<<<NBLK, 512, 0, stream>>>(in, lw, lb, aw, Rt, out, ctr);
}

// Round 7
// 22.903 us; speedup vs baseline: 3.3749x; 3.3749x over previous
//
#include <hip/hip_runtime.h>

#define ALPHA 0.2f
#define BATCH 16
#define WIN 100
#define KN 128          // nodes
#define DE 200          // embed dim
#define IT 8            // i-tile per k_attn block

typedef float v2f __attribute__((ext_vector_type(2)));

// Kernel A: grid 16b x 25dt, 256 thr, zero LDS.
// lane j = t&127, d-quad = dt*8 + (t>>7)*4 (scalar path via readfirstlane).
//   Rt[b][d][j] = sum_w x[w][j]*lw[100+w][d] + lb[d]
//   Lt[b][d][j] = sum_w x[w][j]*lw[w][d]
__global__ __launch_bounds__(256) void k_lin(
    const float* __restrict__ in, const float* __restrict__ lw,
    const float* __restrict__ lb, float* __restrict__ Rt, float* __restrict__ Lt) {
  int blk = blockIdx.x;
  int b = blk / 25, dt = blk % 25;
  int t = threadIdx.x;
  int j = t & (KN - 1);
  int dbase = __builtin_amdgcn_readfirstlane(dt * 8 + (t >> 7) * 4);
  const float* inb = in + (size_t)b * WIN * KN + j;
  const float* lwl = lw + dbase;
  const float* lwr = lw + WIN * DE + dbase;
  float la0 = 0, la1 = 0, la2 = 0, la3 = 0;
  float ra0 = 0, ra1 = 0, ra2 = 0, ra3 = 0;
#pragma unroll 10
  for (int w = 0; w < WIN; ++w) {
    float x = inb[w * KN];
    float4 wl = *reinterpret_cast<const float4*>(lwl + w * DE);
    float4 wr = *reinterpret_cast<const float4*>(lwr + w * DE);
    la0 = fmaf(x, wl.x, la0); la1 = fmaf(x, wl.y, la1);
    la2 = fmaf(x, wl.z, la2); la3 = fmaf(x, wl.w, la3);
    ra0 = fmaf(x, wr.x, ra0); ra1 = fmaf(x, wr.y, ra1);
    ra2 = fmaf(x, wr.z, ra2); ra3 = fmaf(x, wr.w, ra3);
  }
  float4 bb = *reinterpret_cast<const float4*>(lb + dbase);
  float* rp = Rt + ((size_t)b * DE + dbase) * KN + j;
  float* lp = Lt + ((size_t)b * DE + dbase) * KN + j;
  rp[0 * KN] = ra0 + bb.x; rp[1 * KN] = ra1 + bb.y;
  rp[2 * KN] = ra2 + bb.z; rp[3 * KN] = ra3 + bb.w;
  lp[0 * KN] = la0; lp[1 * KN] = la1; lp[2 * KN] = la2; lp[3 * KN] = la3;
}

// Kernel B: per (b, 8-i tile), 1024 thr (j x 8 d-slices of 25 d each).
//   M[ii][j] = sum_d min(Lt[d][i0+ii]+Rt[d][j],0)*aw[d]; ra[j] = sum_d Rt*aw
//   e = ra - 0.8*M (j-invariant per-i shift dropped; softmax unchanged)
//   wave-per-row softmax; PV reads x rows straight from global; sigmoid; store.
__global__ __launch_bounds__(1024) void k_attn_out(
    const float* __restrict__ in, const float* __restrict__ aw,
    const float* __restrict__ Rt, const float* __restrict__ Lt,
    float* __restrict__ out) {
  int blk = blockIdx.x;
  int b = blk >> 4, it = blk & 15;
  int i0 = it * IT;
  int t = threadIdx.x;
  __shared__ float part[8][IT][KN];
  __shared__ float part_r[8][KN];
  __shared__ float ats[IT][132];

  // e-phase: thread (j, dh) covers 25 d's for 8 i's
  {
    int j = t & (KN - 1);
    int db = __builtin_amdgcn_readfirstlane((t >> 7) * 25);
    int dh = t >> 7;
    const float* rtb = Rt + (size_t)b * DE * KN + j;
    const float* ltb = Lt + (size_t)b * DE * KN + i0;   // lane-invariant -> s_load
    v2f acc0 = 0.f, acc1 = 0.f, acc2 = 0.f, acc3 = 0.f;
    float racc = 0.f;
#pragma unroll 5
    for (int dd = 0; dd < 25; ++dd) {
      int d = db + dd;
      float r = rtb[(size_t)d * KN];
      float a = aw[d];
      float4 L0 = *reinterpret_cast<const float4*>(ltb + (size_t)d * KN);
      float4 L1 = *reinterpret_cast<const float4*>(ltb + (size_t)d * KN + 4);
      racc = fmaf(r, a, racc);
      v2f rv = {r, r}, av = {a, a}, z = 0.f;
      v2f p0 = (v2f){L0.x, L0.y} + rv;
      v2f p1 = (v2f){L0.z, L0.w} + rv;
      v2f p2 = (v2f){L1.x, L1.y} + rv;
      v2f p3 = (v2f){L1.z, L1.w} + rv;
      p0 = __builtin_elementwise_min(p0, z);
      p1 = __builtin_elementwise_min(p1, z);
      p2 = __builtin_elementwise_min(p2, z);
      p3 = __builtin_elementwise_min(p3, z);
      acc0 += p0 * av; acc1 += p1 * av; acc2 += p2 * av; acc3 += p3 * av;
    }
    part[dh][0][j] = acc0.x; part[dh][1][j] = acc0.y;
    part[dh][2][j] = acc1.x; part[dh][3][j] = acc1.y;
    part[dh][4][j] = acc2.x; part[dh][5][j] = acc2.y;
    part[dh][6][j] = acc3.x; part[dh][7][j] = acc3.y;
    part_r[dh][j] = racc;
  }
  __syncthreads();

  // softmax: wave r (r<8) owns row r; lanes l and l+64
  {
    int wid = t >> 6;
    if (wid < IT) {
      int r = wid, l = t & 63;
      float ra0 = 0.f, ra1 = 0.f, m0 = 0.f, m1 = 0.f;
#pragma unroll
      for (int dh = 0; dh < 8; ++dh) {
        ra0 += part_r[dh][l];     ra1 += part_r[dh][l + 64];
        m0  += part[dh][r][l];    m1  += part[dh][r][l + 64];
      }
      float e0 = fmaf(m0, -(1.f - ALPHA), ra0);
      float e1 = fmaf(m1, -(1.f - ALPHA), ra1);
      float m = fmaxf(e0, e1);
      for (int off = 32; off; off >>= 1) m = fmaxf(m, __shfl_xor(m, off));
      float p0 = __expf(e0 - m), p1 = __expf(e1 - m);
      float s = p0 + p1;
      for (int off = 32; off; off >>= 1) s += __shfl_xor(s, off);
      float inv = 1.f / s;
      ats[r][l] = p0 * inv;
      ats[r][l + 64] = p1 * inv;
    }
  }
  __syncthreads();

  // PV: thread (w, q<4): out[b][w][i0+q*2+{0,1}]; x rows read from global
  if (t < 4 * WIN) {
    int w = t >> 2, q = t & 3;
    const float* xw = in + ((size_t)b * WIN + w) * KN;
    const float* a0p = &ats[q * 2][0];
    const float* a1p = &ats[q * 2 + 1][0];
    float s0 = 0.f, s1 = 0.f;
#pragma unroll 8
    for (int j = 0; j < KN; j += 4) {
      float4 x4 = *reinterpret_cast<const float4*>(xw + j);
      float4 aa = *reinterpret_cast<const float4*>(a0p + j);
      float4 ab = *reinterpret_cast<const float4*>(a1p + j);
      s0 = fmaf(aa.x, x4.x, s0); s0 = fmaf(aa.y, x4.y, s0);
      s0 = fmaf(aa.z, x4.z, s0); s0 = fmaf(aa.w, x4.w, s0);
      s1 = fmaf(ab.x, x4.x, s1); s1 = fmaf(ab.y, x4.y, s1);
      s1 = fmaf(ab.z, x4.z, s1); s1 = fmaf(ab.w, x4.w, s1);
    }
    float o0 = 1.f / (1.f + __expf(-s0));
    float o1 = 1.f / (1.f + __expf(-s1));
    *reinterpret_cast<float2*>(&out[((size_t)b * WIN + w) * KN + i0 + q * 2]) =
        make_float2(o0, o1);
  }
}

extern "C" void kernel_launch(void* const* d_in, const int* in_sizes, int n_in,
                              void* d_out, int out_size, void* d_ws, size_t ws_size,
                              hipStream_t stream) {
  const float* in = (const float*)d_in[0];   // (16,100,128)
  const float* lw = (const float*)d_in[1];   // (200,200)
  const float* lb = (const float*)d_in[2];   // (200,)
  const float* aw = (const float*)d_in[3];   // (200,)
  float* out = (float*)d_out;                // (16,100,128)

  float* Rt = (float*)d_ws;                          // 16*200*128 floats (1.6 MB)
  float* Lt = Rt + (size_t)BATCH * DE * KN;          // 16*200*128 floats (1.6 MB)

  k_lin     <<<BATCH * 25, 256, 0, stream>>>(in, lw, lb, Rt, Lt);
  k_attn_out<<<BATCH * 16, 1024, 0, stream>>>(in, aw, Rt, Lt, out);
}